// Round 5
// baseline (38.152 us; speedup 1.0000x reference)
//
#include <hip/hip_runtime.h>

typedef float f32x4 __attribute__((ext_vector_type(4)));
typedef int   i32x4 __attribute__((ext_vector_type(4)));
typedef int   i32x8 __attribute__((ext_vector_type(8)));

#define D 128

// ---------------------------------------------------------------------------
// Normalize: one block = 16 rows x 16 lanes. Writes fp8(e4m3) normalized rows
// of both matrices to ws, exact-f32 diag correction partial to diagP, and
// block 0 zeroes the gemm ticket counter (no memset node needed).
// ---------------------------------------------------------------------------
__global__ void normalize_diag_kernel(const float* __restrict__ anc,
                                      const float* __restrict__ pos,
                                      unsigned char* __restrict__ wsA,
                                      unsigned char* __restrict__ wsP,
                                      float* __restrict__ diagP,
                                      int* __restrict__ counter) {
  if (blockIdx.x == 0 && threadIdx.x == 0)
    __hip_atomic_store(counter, 0, __ATOMIC_RELAXED, __HIP_MEMORY_SCOPE_AGENT);
  __shared__ float rowc[16];
  const int t = threadIdx.x;
  const int rl = t >> 4, l16 = t & 15;
  const int row = blockIdx.x * 16 + rl;
  const float* ar = anc + (size_t)row * D + l16 * 8;
  const float* pr = pos + (size_t)row * D + l16 * 8;
  float4 a0 = *(const float4*)ar, a1 = *(const float4*)(ar + 4);
  float4 p0 = *(const float4*)pr, p1 = *(const float4*)(pr + 4);
  float av[8] = {a0.x, a0.y, a0.z, a0.w, a1.x, a1.y, a1.z, a1.w};
  float pv[8] = {p0.x, p0.y, p0.z, p0.w, p1.x, p1.y, p1.z, p1.w};
  float ssa = 0.f, ssp = 0.f;
#pragma unroll
  for (int k = 0; k < 8; ++k) { ssa += av[k] * av[k]; ssp += pv[k] * pv[k]; }
#pragma unroll
  for (int off = 1; off < 16; off <<= 1) {
    ssa += __shfl_xor(ssa, off);
    ssp += __shfl_xor(ssp, off);
  }
  const float sa = 1.f / fmaxf(sqrtf(ssa), 1e-8f);
  const float sp = 1.f / fmaxf(sqrtf(ssp), 1e-8f);
  float an[8], pn[8];
  float dot = 0.f;
#pragma unroll
  for (int k = 0; k < 8; ++k) {
    an[k] = av[k] * sa;
    pn[k] = pv[k] * sp;
    dot += an[k] * pn[k];
  }
  // pack 8 fp8 e4m3 per matrix (2 ints)
  int wa0 = __builtin_amdgcn_cvt_pk_fp8_f32(an[0], an[1], 0, false);
  wa0 = __builtin_amdgcn_cvt_pk_fp8_f32(an[2], an[3], wa0, true);
  int wa1 = __builtin_amdgcn_cvt_pk_fp8_f32(an[4], an[5], 0, false);
  wa1 = __builtin_amdgcn_cvt_pk_fp8_f32(an[6], an[7], wa1, true);
  int wp0 = __builtin_amdgcn_cvt_pk_fp8_f32(pn[0], pn[1], 0, false);
  wp0 = __builtin_amdgcn_cvt_pk_fp8_f32(pn[2], pn[3], wp0, true);
  int wp1 = __builtin_amdgcn_cvt_pk_fp8_f32(pn[4], pn[5], 0, false);
  wp1 = __builtin_amdgcn_cvt_pk_fp8_f32(pn[6], pn[7], wp1, true);
  *(int2*)(wsA + (size_t)row * D + l16 * 8) = make_int2(wa0, wa1);
  *(int2*)(wsP + (size_t)row * D + l16 * 8) = make_int2(wp0, wp1);
#pragma unroll
  for (int off = 1; off < 16; off <<= 1) dot += __shfl_xor(dot, off);
  if (l16 == 0) rowc[rl] = 1.f - dot - fmaxf(dot, 0.f);
  __syncthreads();
  if (t == 0) {
    float s = 0.f;
#pragma unroll
    for (int i = 0; i < 16; ++i) s += rowc[i];
    diagP[blockIdx.x] = s;
  }
}

// ---------------------------------------------------------------------------
// fp8 MX GEMM: 512 blocks (2/CU), 8 waves (2 wrow x 4 wcol), wave tile 64x32.
// Block = 128-row panel x 1024-col group (8 col tiles of 128).
// A (128x128 fp8, 16KB) staged once, fragments hoisted to 32 VGPR; B tiles
// (16KB) double-buffered. One mfma_scale_f32_16x16x128 covers full K per
// fragment pair (scales = 0x7F = 1.0). LDS rows 128B, chunk^(row&7) swizzle
// on the GLOBAL source (linear LDS dest); identical A/B layout makes any
// K-permutation harmless. Epilogue: relu-sum + ticket-fused finalize.
// ---------------------------------------------------------------------------
__global__ __launch_bounds__(512, 4) void gemm_relu_sum_kernel(
    const unsigned char* __restrict__ wsA,
    const unsigned char* __restrict__ wsP,
    float* __restrict__ partials, const float* __restrict__ diagP,
    int* __restrict__ counter, float* __restrict__ out, float invBB,
    int nBlocks) {
  __shared__ __align__(16) unsigned char ldsA[128 * 128];      // 16 KB
  __shared__ __align__(16) unsigned char ldsB[2][128 * 128];   // 2 x 16 KB
  __shared__ float wpart[8];
  __shared__ int lastFlag;
  const int tid = threadIdx.x;
  const int w = tid >> 6, l = tid & 63;
  const int r16 = l & 15, kg = l >> 4;
  const int wrow = w >> 2, wcol = w & 3;   // 2 x 4 waves, wave tile 64x32
  const int rp = blockIdx.x >> 3;          // row panel 0..63 (128 rows)
  const int cg = blockIdx.x & 7;           // col group 0..7 (XCD-pinned)

  const unsigned char* gA = wsA + (size_t)rp * 128 * D;

  // ---- stage A panel (16KB): linear LDS dest, swizzled global source
#pragma unroll
  for (int it = 0; it < 2; ++it) {
    const int g = it * 512 + tid;          // 16B chunk 0..1023
    const int r = g >> 3, s = g & 7;
    const int goff = r * 128 + ((s ^ (r & 7)) * 16);
    const int lbase = (it * 512 + w * 64) * 16;
    __builtin_amdgcn_global_load_lds(
        (const __attribute__((address_space(1))) char*)(gA + goff),
        (__attribute__((address_space(3))) char*)((char*)ldsA + lbase), 16, 0, 0);
  }
  // ---- stage B tile 0
  {
    const unsigned char* gBt = wsP + (size_t)(cg * 1024) * D;
#pragma unroll
    for (int it = 0; it < 2; ++it) {
      const int g = it * 512 + tid;
      const int r = g >> 3, s = g & 7;
      const int goff = r * 128 + ((s ^ (r & 7)) * 16);
      const int lbase = (it * 512 + w * 64) * 16;
      __builtin_amdgcn_global_load_lds(
          (const __attribute__((address_space(1))) char*)(gBt + goff),
          (__attribute__((address_space(3))) char*)((char*)ldsB[0] + lbase), 16, 0, 0);
    }
  }
  __syncthreads();

  // ---- hoist A fragments (4 x 32B), reused across all 8 column tiles
  i32x8 af[4];
#pragma unroll
  for (int m = 0; m < 4; ++m) {
    const int r = wrow * 64 + m * 16 + r16;
    const unsigned char* base = (const unsigned char*)ldsA + r * 128;
    i32x4 lo = *(const i32x4*)(base + (((2 * kg) ^ (r & 7)) * 16));
    i32x4 hi = *(const i32x4*)(base + (((2 * kg + 1) ^ (r & 7)) * 16));
    af[m] = __builtin_shufflevector(lo, hi, 0, 1, 2, 3, 4, 5, 6, 7);
  }

  float s = 0.f;
  for (int t = 0; t < 8; ++t) {
    if (t < 7) {   // stage next B tile (latency hides under MFMA phase)
      const unsigned char* gBt = wsP + (size_t)(cg * 1024 + (t + 1) * 128) * D;
      char* lB = (char*)ldsB[(t + 1) & 1];
#pragma unroll
      for (int it = 0; it < 2; ++it) {
        const int g = it * 512 + tid;
        const int r = g >> 3, sl = g & 7;
        const int goff = r * 128 + ((sl ^ (r & 7)) * 16);
        const int lbase = (it * 512 + w * 64) * 16;
        __builtin_amdgcn_global_load_lds(
            (const __attribute__((address_space(1))) char*)(gBt + goff),
            (__attribute__((address_space(3))) char*)(lB + lbase), 16, 0, 0);
      }
    }

    const unsigned char* lB = (const unsigned char*)ldsB[t & 1];
    i32x8 bfr[2];
#pragma unroll
    for (int n = 0; n < 2; ++n) {
      const int r = wcol * 32 + n * 16 + r16;
      const unsigned char* base = lB + r * 128;
      i32x4 lo = *(const i32x4*)(base + (((2 * kg) ^ (r & 7)) * 16));
      i32x4 hi = *(const i32x4*)(base + (((2 * kg + 1) ^ (r & 7)) * 16));
      bfr[n] = __builtin_shufflevector(lo, hi, 0, 1, 2, 3, 4, 5, 6, 7);
    }

    f32x4 acc[4][2] = {};
#pragma unroll
    for (int m = 0; m < 4; ++m)
#pragma unroll
      for (int n = 0; n < 2; ++n)
        acc[m][n] = __builtin_amdgcn_mfma_scale_f32_16x16x128_f8f6f4(
            af[m], bfr[n], acc[m][n], 0, 0,   // cbsz=fp8, blgp=fp8
            0, 0x7f7f7f7f, 0, 0x7f7f7f7f);    // scales = 1.0

    // relu-sum this tile (layout-oblivious)
#pragma unroll
    for (int m = 0; m < 4; ++m)
#pragma unroll
      for (int n = 0; n < 2; ++n)
#pragma unroll
        for (int q = 0; q < 4; ++q) s += fmaxf(acc[m][n][q], 0.f);

    __syncthreads();
  }

  // ---- block partial
#pragma unroll
  for (int off = 32; off >= 1; off >>= 1) s += __shfl_xor(s, off);
  if (l == 0) wpart[w] = s;
  __syncthreads();
  if (tid == 0) {
    float b = 0.f;
#pragma unroll
    for (int i = 0; i < 8; ++i) b += wpart[i];
    __hip_atomic_store(&partials[blockIdx.x], b, __ATOMIC_RELAXED,
                       __HIP_MEMORY_SCOPE_AGENT);
    __threadfence();
    const int ticket = __hip_atomic_fetch_add(counter, 1, __ATOMIC_ACQ_REL,
                                              __HIP_MEMORY_SCOPE_AGENT);
    lastFlag = (ticket == nBlocks - 1) ? 1 : 0;
  }
  __syncthreads();

  // ---- last block finalizes: sum 512 partials + 512 diag partials
  if (lastFlag) {
    __threadfence();
    float v = __hip_atomic_load(&partials[tid], __ATOMIC_RELAXED,
                                __HIP_MEMORY_SCOPE_AGENT) +
              diagP[tid];
#pragma unroll
    for (int off = 32; off >= 1; off >>= 1) v += __shfl_xor(v, off);
    if (l == 0) wpart[w] = v;
    __syncthreads();
    if (tid == 0) {
      float tot = 0.f;
#pragma unroll
      for (int i = 0; i < 8; ++i) tot += wpart[i];
      out[0] = tot * invBB;
    }
  }
}

extern "C" void kernel_launch(void* const* d_in, const int* in_sizes, int n_in,
                              void* d_out, int out_size, void* d_ws, size_t ws_size,
                              hipStream_t stream) {
  const float* pos = (const float*)d_in[0];  // hid_positive
  const float* anc = (const float*)d_in[1];  // hid_anchor
  const int B = in_sizes[0] / D;             // 8192

  char* ws = (char*)d_ws;
  unsigned char* wsA = (unsigned char*)ws;                      // B*D fp8 (1MB)
  unsigned char* wsP = (unsigned char*)(ws + (size_t)B * D);    // B*D fp8 (1MB)
  float* partials = (float*)(ws + (size_t)2 * B * D);           // 512 f32
  float* diagP = partials + 512;                                // 512 f32
  int* counter = (int*)(diagP + 512);

  const int nDiag = B / 16;                  // 512
  const int nBlocks = 512;                   // 2 blocks/CU, fully resident
  const float invBB = 1.0f / ((float)B * (float)B);

  normalize_diag_kernel<<<nDiag, 256, 0, stream>>>(anc, pos, wsA, wsP, diagP,
                                                   counter);
  gemm_relu_sum_kernel<<<nBlocks, 512, 0, stream>>>(wsA, wsP, partials, diagP,
                                                    counter, (float*)d_out,
                                                    invBB, nBlocks);
}

// Round 6
// 30.227 us; speedup vs baseline: 1.2622x; 1.2622x over previous
//
#include <hip/hip_runtime.h>

typedef float f32x4 __attribute__((ext_vector_type(4)));
typedef int   i32x4 __attribute__((ext_vector_type(4)));
typedef int   i32x8 __attribute__((ext_vector_type(8)));

#define D 128

// ---------------------------------------------------------------------------
// Normalize: one block = 16 rows x 16 lanes. Writes fp8(e4m3) normalized rows
// of both matrices to ws, exact-f32 diag correction partial to diagP, and
// block 0 zeroes the gemm ticket counter (no memset node needed).
// (Verbatim from R5 — absmax 0.0 validated this path end-to-end.)
// ---------------------------------------------------------------------------
__global__ void normalize_diag_kernel(const float* __restrict__ anc,
                                      const float* __restrict__ pos,
                                      unsigned char* __restrict__ wsA,
                                      unsigned char* __restrict__ wsP,
                                      float* __restrict__ diagP,
                                      int* __restrict__ counter) {
  if (blockIdx.x == 0 && threadIdx.x == 0)
    __hip_atomic_store(counter, 0, __ATOMIC_RELAXED, __HIP_MEMORY_SCOPE_AGENT);
  __shared__ float rowc[16];
  const int t = threadIdx.x;
  const int rl = t >> 4, l16 = t & 15;
  const int row = blockIdx.x * 16 + rl;
  const float* ar = anc + (size_t)row * D + l16 * 8;
  const float* pr = pos + (size_t)row * D + l16 * 8;
  float4 a0 = *(const float4*)ar, a1 = *(const float4*)(ar + 4);
  float4 p0 = *(const float4*)pr, p1 = *(const float4*)(pr + 4);
  float av[8] = {a0.x, a0.y, a0.z, a0.w, a1.x, a1.y, a1.z, a1.w};
  float pv[8] = {p0.x, p0.y, p0.z, p0.w, p1.x, p1.y, p1.z, p1.w};
  float ssa = 0.f, ssp = 0.f;
#pragma unroll
  for (int k = 0; k < 8; ++k) { ssa += av[k] * av[k]; ssp += pv[k] * pv[k]; }
#pragma unroll
  for (int off = 1; off < 16; off <<= 1) {
    ssa += __shfl_xor(ssa, off);
    ssp += __shfl_xor(ssp, off);
  }
  const float sa = 1.f / fmaxf(sqrtf(ssa), 1e-8f);
  const float sp = 1.f / fmaxf(sqrtf(ssp), 1e-8f);
  float an[8], pn[8];
  float dot = 0.f;
#pragma unroll
  for (int k = 0; k < 8; ++k) {
    an[k] = av[k] * sa;
    pn[k] = pv[k] * sp;
    dot += an[k] * pn[k];
  }
  int wa0 = __builtin_amdgcn_cvt_pk_fp8_f32(an[0], an[1], 0, false);
  wa0 = __builtin_amdgcn_cvt_pk_fp8_f32(an[2], an[3], wa0, true);
  int wa1 = __builtin_amdgcn_cvt_pk_fp8_f32(an[4], an[5], 0, false);
  wa1 = __builtin_amdgcn_cvt_pk_fp8_f32(an[6], an[7], wa1, true);
  int wp0 = __builtin_amdgcn_cvt_pk_fp8_f32(pn[0], pn[1], 0, false);
  wp0 = __builtin_amdgcn_cvt_pk_fp8_f32(pn[2], pn[3], wp0, true);
  int wp1 = __builtin_amdgcn_cvt_pk_fp8_f32(pn[4], pn[5], 0, false);
  wp1 = __builtin_amdgcn_cvt_pk_fp8_f32(pn[6], pn[7], wp1, true);
  *(int2*)(wsA + (size_t)row * D + l16 * 8) = make_int2(wa0, wa1);
  *(int2*)(wsP + (size_t)row * D + l16 * 8) = make_int2(wp0, wp1);
#pragma unroll
  for (int off = 1; off < 16; off <<= 1) dot += __shfl_xor(dot, off);
  if (l16 == 0) rowc[rl] = 1.f - dot - fmaxf(dot, 0.f);
  __syncthreads();
  if (t == 0) {
    float s = 0.f;
#pragma unroll
    for (int i = 0; i < 16; ++i) s += rowc[i];
    diagP[blockIdx.x] = s;
  }
}

// ---------------------------------------------------------------------------
// fp8 MX GEMM: 256 blocks (1/CU, persistent), 8 waves (2 wrow x 4 wcol),
// wave tile 128x32 -> 16 MFMAs/tile/wave (~1100 cyc/SIMD) hides B staging.
// Block = 256-row panel x 1024-col group (8 col tiles of 128).
// A (256x128 fp8, 32KB) staged once, af[8] hoisted to 64 VGPR; B tiles (16KB)
// double-buffered. launch_bounds(512,2): 256-reg cap, no spill (~180 live).
// One mfma_scale_f32_16x16x128 covers full K per fragment pair (scale 0x7F).
// Epilogue: relu-sum (layout-oblivious) + ticket-fused finalize.
// ---------------------------------------------------------------------------
__global__ __launch_bounds__(512, 2) void gemm_relu_sum_kernel(
    const unsigned char* __restrict__ wsA,
    const unsigned char* __restrict__ wsP,
    float* __restrict__ partials, const float* __restrict__ diagP,
    int* __restrict__ counter, float* __restrict__ out, float invBB,
    int nBlocks) {
  __shared__ __align__(16) unsigned char ldsA[256 * 128];      // 32 KB
  __shared__ __align__(16) unsigned char ldsB[2][128 * 128];   // 2 x 16 KB
  __shared__ float wpart[8];
  __shared__ int lastFlag;
  const int tid = threadIdx.x;
  const int w = tid >> 6, l = tid & 63;
  const int r16 = l & 15, kg = l >> 4;
  const int wrow = w >> 2, wcol = w & 3;   // wave tile 128 rows x 32 cols
  const int rp = blockIdx.x >> 3;          // row panel 0..31 (256 rows)
  const int cg = blockIdx.x & 7;           // col group 0..7 (XCD-pinned)

  const unsigned char* gA = wsA + (size_t)rp * 256 * D;

  // ---- stage A panel (32KB, 4 rounds): linear LDS dest, swizzled source
#pragma unroll
  for (int it = 0; it < 4; ++it) {
    const int g = it * 512 + tid;          // 16B chunk 0..2047
    const int r = g >> 3, sl = g & 7;
    const int goff = r * 128 + ((sl ^ (r & 7)) * 16);
    const int lbase = (it * 512 + w * 64) * 16;
    __builtin_amdgcn_global_load_lds(
        (const __attribute__((address_space(1))) char*)(gA + goff),
        (__attribute__((address_space(3))) char*)((char*)ldsA + lbase), 16, 0, 0);
  }
  // ---- stage B tile 0 (16KB, 2 rounds)
  {
    const unsigned char* gBt = wsP + (size_t)(cg * 1024) * D;
#pragma unroll
    for (int it = 0; it < 2; ++it) {
      const int g = it * 512 + tid;        // 16B chunk 0..1023
      const int r = g >> 3, sl = g & 7;
      const int goff = r * 128 + ((sl ^ (r & 7)) * 16);
      const int lbase = (it * 512 + w * 64) * 16;
      __builtin_amdgcn_global_load_lds(
          (const __attribute__((address_space(1))) char*)(gBt + goff),
          (__attribute__((address_space(3))) char*)((char*)ldsB[0] + lbase), 16, 0, 0);
    }
  }
  __syncthreads();

  // ---- hoist A fragments (8 x 32B = 64 VGPR), reused across all 8 tiles
  i32x8 af[8];
#pragma unroll
  for (int m = 0; m < 8; ++m) {
    const int r = wrow * 128 + m * 16 + r16;
    const unsigned char* base = (const unsigned char*)ldsA + r * 128;
    i32x4 lo = *(const i32x4*)(base + (((2 * kg) ^ (r & 7)) * 16));
    i32x4 hi = *(const i32x4*)(base + (((2 * kg + 1) ^ (r & 7)) * 16));
    af[m] = __builtin_shufflevector(lo, hi, 0, 1, 2, 3, 4, 5, 6, 7);
  }

  float s = 0.f;
  for (int t = 0; t < 8; ++t) {
    if (t < 7) {   // stage next B tile (latency hides under 16-MFMA phase)
      const unsigned char* gBt = wsP + (size_t)(cg * 1024 + (t + 1) * 128) * D;
      char* lB = (char*)ldsB[(t + 1) & 1];
#pragma unroll
      for (int it = 0; it < 2; ++it) {
        const int g = it * 512 + tid;
        const int r = g >> 3, sl = g & 7;
        const int goff = r * 128 + ((sl ^ (r & 7)) * 16);
        const int lbase = (it * 512 + w * 64) * 16;
        __builtin_amdgcn_global_load_lds(
            (const __attribute__((address_space(1))) char*)(gBt + goff),
            (__attribute__((address_space(3))) char*)(lB + lbase), 16, 0, 0);
      }
    }

    const unsigned char* lB = (const unsigned char*)ldsB[t & 1];
    i32x8 bfr[2];
#pragma unroll
    for (int n = 0; n < 2; ++n) {
      const int r = wcol * 32 + n * 16 + r16;
      const unsigned char* base = lB + r * 128;
      i32x4 lo = *(const i32x4*)(base + (((2 * kg) ^ (r & 7)) * 16));
      i32x4 hi = *(const i32x4*)(base + (((2 * kg + 1) ^ (r & 7)) * 16));
      bfr[n] = __builtin_shufflevector(lo, hi, 0, 1, 2, 3, 4, 5, 6, 7);
    }

    f32x4 acc[8][2] = {};
    __builtin_amdgcn_s_setprio(1);
#pragma unroll
    for (int m = 0; m < 8; ++m)
#pragma unroll
      for (int n = 0; n < 2; ++n)
        acc[m][n] = __builtin_amdgcn_mfma_scale_f32_16x16x128_f8f6f4(
            af[m], bfr[n], acc[m][n], 0, 0,   // cbsz=fp8, blgp=fp8
            0, 0x7f7f7f7f, 0, 0x7f7f7f7f);    // scales = 1.0
    __builtin_amdgcn_s_setprio(0);

    // relu-sum this tile (layout-oblivious)
#pragma unroll
    for (int m = 0; m < 8; ++m)
#pragma unroll
      for (int n = 0; n < 2; ++n)
#pragma unroll
        for (int q = 0; q < 4; ++q) s += fmaxf(acc[m][n][q], 0.f);

    __syncthreads();
  }

  // ---- block partial
#pragma unroll
  for (int off = 32; off >= 1; off >>= 1) s += __shfl_xor(s, off);
  if (l == 0) wpart[w] = s;
  __syncthreads();
  if (tid == 0) {
    float b = 0.f;
#pragma unroll
    for (int i = 0; i < 8; ++i) b += wpart[i];
    __hip_atomic_store(&partials[blockIdx.x], b, __ATOMIC_RELAXED,
                       __HIP_MEMORY_SCOPE_AGENT);
    __threadfence();
    const int ticket = __hip_atomic_fetch_add(counter, 1, __ATOMIC_ACQ_REL,
                                              __HIP_MEMORY_SCOPE_AGENT);
    lastFlag = (ticket == nBlocks - 1) ? 1 : 0;
  }
  __syncthreads();

  // ---- last block finalizes: 256 gemm partials + 512 diag partials
  if (lastFlag) {
    __threadfence();
    float v = diagP[tid];
    if (tid < nBlocks)
      v += __hip_atomic_load(&partials[tid], __ATOMIC_RELAXED,
                             __HIP_MEMORY_SCOPE_AGENT);
#pragma unroll
    for (int off = 32; off >= 1; off >>= 1) v += __shfl_xor(v, off);
    if (l == 0) wpart[w] = v;
    __syncthreads();
    if (tid == 0) {
      float tot = 0.f;
#pragma unroll
      for (int i = 0; i < 8; ++i) tot += wpart[i];
      out[0] = tot * invBB;
    }
  }
}

extern "C" void kernel_launch(void* const* d_in, const int* in_sizes, int n_in,
                              void* d_out, int out_size, void* d_ws, size_t ws_size,
                              hipStream_t stream) {
  const float* pos = (const float*)d_in[0];  // hid_positive
  const float* anc = (const float*)d_in[1];  // hid_anchor
  const int B = in_sizes[0] / D;             // 8192

  char* ws = (char*)d_ws;
  unsigned char* wsA = (unsigned char*)ws;                      // B*D fp8 (1MB)
  unsigned char* wsP = (unsigned char*)(ws + (size_t)B * D);    // B*D fp8 (1MB)
  float* partials = (float*)(ws + (size_t)2 * B * D);           // 256 f32
  float* diagP = partials + 256;                                // 512 f32
  int* counter = (int*)(diagP + 512);

  const int nDiag = B / 16;                  // 512
  const int nBlocks = 256;                   // persistent: 1 block/CU
  const float invBB = 1.0f / ((float)B * (float)B);

  normalize_diag_kernel<<<nDiag, 256, 0, stream>>>(anc, pos, wsA, wsP, diagP,
                                                   counter);
  gemm_relu_sum_kernel<<<nBlocks, 512, 0, stream>>>(wsA, wsP, partials, diagP,
                                                    counter, (float*)d_out,
                                                    invBB, nBlocks);
}